// Round 19
// baseline (358.053 us; speedup 1.0000x reference)
//
#include <hip/hip_runtime.h>
#include <stdint.h>

// f32 I/O, bf16 MFMA internals. Attention v14 = r18 (compacted keys, step-kb,
// KV-split x2, 4-deep rings) with: bf16 O-partials (po), per-lane l partial
// reduced once in epilogue, and empty tail bodies truncated (bodies_run).
// Masked-q rows = mean(ALL V) (reference's -1e9 f32 absorption).

typedef unsigned short u16;
typedef __attribute__((ext_vector_type(4))) float f32x4;
typedef __attribute__((ext_vector_type(8))) short short8;
typedef __attribute__((ext_vector_type(4))) short s16x4;
typedef __attribute__((ext_vector_type(8))) __bf16 bf16x8;

__device__ __forceinline__ float b2f(u16 u){
  union { unsigned int i; float f; } v; v.i = ((unsigned int)u) << 16; return v.f;
}
__device__ __forceinline__ u16 f2b(float f){
  union { float f; unsigned int i; } v; v.f = f;
  unsigned int u = v.i;
  u = u + 0x7FFFu + ((u >> 16) & 1u);   // RNE
  return (u16)(u >> 16);
}
__device__ __forceinline__ f32x4 mfma16(short8 a, short8 b, f32x4 c){
  return __builtin_amdgcn_mfma_f32_16x16x32_bf16(
      __builtin_bit_cast(bf16x8, a), __builtin_bit_cast(bf16x8, b), c, 0, 0, 0);
}
__device__ __forceinline__ void gload16(const void* g, void* l){
  void* gnc = const_cast<void*>(g);
  __builtin_amdgcn_global_load_lds((__attribute__((address_space(1))) void*)gnc,
                                   (__attribute__((address_space(3))) void*)l, 16, 0, 0);
}

// ---------------- merged f32 -> bf16 weight conversion (4 segments) ---------
__global__ __launch_bounds__(256) void cvt4_k(
    const float* __restrict__ s0, u16* __restrict__ d0,
    const float* __restrict__ s1, u16* __restrict__ d1,
    const float* __restrict__ s2, u16* __restrict__ d2,
    const float* __restrict__ s3, u16* __restrict__ d3)
{
  int i = blockIdx.x*256 + threadIdx.x;
  const float* src; u16* dst; int j = i;
  if (j < 442368){ src = s0; dst = d0; }
  else if ((j -= 442368) < 147456){ src = s1; dst = d1; }
  else if ((j -= 147456) < 589824){ src = s2; dst = d2; }
  else { j -= 589824; src = s3; dst = d3; }
  float4 v = *(const float4*)(src + (size_t)j*4);
  s16x4 o; o[0]=(short)f2b(v.x); o[1]=(short)f2b(v.y);
  o[2]=(short)f2b(v.z); o[3]=(short)f2b(v.w);
  *(s16x4*)(dst + (size_t)j*4) = o;
}

// ---------------- per-batch valid-key scan (1 wave per batch) ---------------
__global__ __launch_bounds__(64) void scan_k(const int* __restrict__ mask,
    int* __restrict__ idx, int* __restrict__ nvalid, float* __restrict__ vm)
{
  int b = blockIdx.x, l = threadIdx.x;
  const int* m = mask + b*4096;
  int base = 0;
  for (int i0 = 0; i0 < 4096; i0 += 64){
    int v = m[i0 + l] != 0;
    unsigned long long bal = __ballot(v);
    int pre = __popcll(bal & ((1ull << l) - 1ull));
    if (v) idx[b*4096 + base + pre] = i0 + l;
    base += (int)__popcll(bal);
  }
  if (l == 0) nvalid[b] = base;
  if (b == 0) for (int i = l; i < 24*64; i += 64) vm[i] = 0.f;
}

// ---------------- adaLN modulation: mod[b][6*768] = c @ Wada^T + bada --------
__global__ __launch_bounds__(256) void mod_k(const float* __restrict__ c,
    const float* __restrict__ Wada, const float* __restrict__ bada, float* __restrict__ modb)
{
  int o = blockIdx.x*4 + (threadIdx.x >> 6);   // 0..9215
  int l = threadIdx.x & 63;
  int b = o / 4608, j = o - b*4608;
  const float* cp = c + b*768;
  const float* wp = Wada + (size_t)j*768;
  float s = 0.f;
  for (int k = l; k < 768; k += 64) s += cp[k] * wp[k];
  #pragma unroll
  for (int d=1; d<64; d<<=1) s += __shfl_xor(s, d);
  if (l == 0) modb[o] = s + bada[j];
}

// ---------------- LayerNorm (no affine) * w * (1+scale) + shift -> bf16 -----
__global__ __launch_bounds__(256) void ln_mod_k(const float* __restrict__ xin,
    u16* __restrict__ out, const float* __restrict__ lnw, const float* __restrict__ modb,
    int shift_c, int scale_c)
{
  int row = blockIdx.x;             // 0..8191 (b*4096+s)
  int b = row >> 12;
  const float* xp = xin + (size_t)row*768;
  int t = threadIdx.x;
  float v[3]; float s = 0.f, s2 = 0.f;
  #pragma unroll
  for (int i=0;i<3;i++){ float f = xp[t + i*256]; v[i] = f; s += f; s2 += f*f; }
  #pragma unroll
  for (int d=1; d<64; d<<=1){ s += __shfl_xor(s, d); s2 += __shfl_xor(s2, d); }
  __shared__ float rs_[4], rs2_[4];
  int w = t >> 6;
  if ((t & 63) == 0){ rs_[w] = s; rs2_[w] = s2; }
  __syncthreads();
  s  = rs_[0]+rs_[1]+rs_[2]+rs_[3];
  s2 = rs2_[0]+rs2_[1]+rs2_[2]+rs2_[3];
  float mu  = s * (1.f/768.f);
  float var = fmaxf(s2 * (1.f/768.f) - mu*mu, 0.f);
  float rstd = rsqrtf(var + 1e-5f);
  const float* scp = modb + b*4608 + scale_c*768;
  const float* shp = modb + b*4608 + shift_c*768;
  #pragma unroll
  for (int i=0;i<3;i++){
    int d = t + i*256;
    float f = (v[i]-mu)*rstd*lnw[d];
    f = f*(1.f + scp[d]) + shp[d];
    out[(size_t)row*768 + d] = f2b(f);
  }
}

// ---------------- 128x128 BK=64 GEMM, C = A[M,K] @ Bt[N,K]^T, fused epilogues
template<int EPI>
__global__ __launch_bounds__(256) void gemm_k(
    const u16* __restrict__ A, const u16* __restrict__ Bt, void* __restrict__ Cv,
    int M, int N, int K,
    const float* __restrict__ addend, const float* __restrict__ modb,
    const float* __restrict__ bias,
    const float* __restrict__ cosb, const float* __restrict__ sinb,
    u16* __restrict__ qO, u16* __restrict__ kO, u16* __restrict__ vO)
{
  __shared__ __align__(16) u16 As[128*64];
  __shared__ __align__(16) u16 Bs[128*64];
  const int bm = blockIdx.x, bn = blockIdx.y;
  const int tid = threadIdx.x;
  const int w = tid >> 6, l = tid & 63;
  const int wr = w >> 1, wc = w & 1;
  const int l15 = l & 15, lg = l >> 4;
  f32x4 acc[4][4] = {};

  for (int k0 = 0; k0 < K; k0 += 64){
    #pragma unroll
    for (int i=0;i<4;i++){
      int e = i*256 + tid;
      int r = e >> 3, ch = e & 7;
      int sc = ch ^ (r & 7);
      gload16(A  + (size_t)(bm*128 + r)*K + k0 + sc*8, &As[e*8]);
      gload16(Bt + (size_t)(bn*128 + r)*K + k0 + sc*8, &Bs[e*8]);
    }
    __syncthreads();
    #pragma unroll
    for (int kk=0;kk<2;kk++){
      short8 af[4], bfv[4];
      #pragma unroll
      for (int i=0;i<4;i++){
        int ra = wr*64 + i*16 + l15;
        af[i]  = *(const short8*)&As[ra*64 + (((kk*4)+lg) ^ (ra&7))*8];
        int rb = wc*64 + i*16 + l15;
        bfv[i] = *(const short8*)&Bs[rb*64 + (((kk*4)+lg) ^ (rb&7))*8];
      }
      #pragma unroll
      for (int m=0;m<4;m++)
        #pragma unroll
        for (int n=0;n<4;n++)
          acc[m][n] = mfma16(af[m], bfv[n], acc[m][n]);
    }
    __syncthreads();
  }

  if constexpr (EPI == 4){
    const int colseg = bn*128 + wc*64;
    const int qi = colseg / 768;            // 0=q 1=k 2=v
    const int h  = (colseg - qi*768) >> 6;  // 0..11
    const float qs = (qi == 0) ? 0.1803368801111601f : 1.f;  // 0.125*log2(e)
    u16* dst = (qi == 0) ? qO : (qi == 1) ? kO : vO;
    #pragma unroll
    for (int m=0;m<4;m++){
      #pragma unroll
      for (int r=0;r<4;r++){
        int row = bm*128 + wr*64 + m*16 + lg*4 + r;
        int s = row & 4095, bb = row >> 12;
        size_t obase = ((size_t)(bb*12 + h)*4096 + s)*64;
        #pragma unroll
        for (int n2=0;n2<2;n2++){
          int d1 = n2*16 + l15;            // < 32
          int d2 = d1 + 32;
          float c1 = cosb[s*64 + d1], s1 = sinb[s*64 + d1];
          float c2 = cosb[s*64 + d2], s2 = sinb[s*64 + d2];
          float x1 = acc[m][n2][r], x2 = acc[m][n2+2][r];
          dst[obase + d1] = f2b((x1*c1 - x2*s1)*qs);
          dst[obase + d2] = f2b((x2*c2 + x1*s2)*qs);
        }
      }
    }
    return;
  }

  #pragma unroll
  for (int m=0;m<4;m++){
    int row0 = bm*128 + wr*64 + m*16 + lg*4;
    #pragma unroll
    for (int n=0;n<4;n++){
      int col = bn*128 + wc*64 + n*16 + l15;
      #pragma unroll
      for (int r=0;r<4;r++){
        int row = row0 + r;
        size_t idx = (size_t)row*N + col;
        float v = acc[m][n][r];
        if constexpr (EPI == 0){
          ((u16*)Cv)[idx] = f2b(v);
        } else if constexpr (EPI == 1){
          float g = modb[(row>>12)*4608 + 2*768 + col];   // gate_msa
          ((float*)Cv)[idx] = addend[idx] + g*v;
        } else if constexpr (EPI == 2){
          float u = v + bias[col];
          float t0 = 0.7978845608028654f*(u + 0.044715f*u*u*u);
          ((u16*)Cv)[idx] = f2b(0.5f*u*(1.0f + tanhf(t0)));
        } else if constexpr (EPI == 3){
          float g = modb[(row>>12)*4608 + 5*768 + col];   // gate_mlp
          float u = v + bias[col];
          ((float*)Cv)[idx] = addend[idx] + g*u;
        }
      }
    }
  }
}

// ------- gather valid keys: kc rows + V transpose-gather into vTc -----------
__global__ __launch_bounds__(256) void gath_k(const u16* __restrict__ kT,
    const u16* __restrict__ vS, const int* __restrict__ idx,
    const int* __restrict__ nvalid, u16* __restrict__ kc, u16* __restrict__ vTc)
{
  __shared__ __align__(16) u16 tile[64][72];
  int j0 = blockIdx.x*64, bh = blockIdx.y;
  int b = bh / 12;
  int nv = nvalid[b];
  int npad = (nv + 511) & ~511;
  if (j0 >= npad) return;
  int t = threadIdx.x;
  #pragma unroll
  for (int i=0;i<2;i++){
    int e = i*256 + t;
    int r = e >> 3, ch = e & 7;
    int j = j0 + r;
    short8 kv8 = {}, vv8 = {};
    if (j < nv){
      int src = idx[b*4096 + j];
      kv8 = *(const short8*)(kT + ((size_t)bh*4096 + src)*64 + ch*8);
      vv8 = *(const short8*)(vS + ((size_t)bh*4096 + src)*64 + ch*8);
    }
    *(short8*)(kc + ((size_t)bh*4096 + j)*64 + ch*8) = kv8;
    *(short8*)&tile[r][ch*8] = vv8;
  }
  __syncthreads();
  #pragma unroll
  for (int i=0;i<2;i++){
    int e = i*256 + t;
    int dd = e >> 3, s0 = (e & 7)*8;
    short8 ov;
    #pragma unroll
    for (int k2=0;k2<8;k2++) ov[k2] = (short)tile[s0+k2][dd];
    *(short8*)(vTc + ((size_t)bh*64 + dd)*4096 + j0 + s0) = ov;
  }
}

// ---------------- vmean over ALL 4096 V rows (for masked-q rows) ------------
__global__ __launch_bounds__(256) void vmean2_k(const u16* __restrict__ vS,
                                                float* __restrict__ vm)
{
  int bh = blockIdx.y, r0 = blockIdx.x*256;
  int t = threadIdx.x, d = t & 63, g = t >> 6;
  const u16* p = vS + ((size_t)bh*4096 + r0)*64 + d;
  float s = 0.f;
  for (int k = g; k < 256; k += 4) s += b2f(p[(size_t)k*64]);
  __shared__ float red[4][64];
  red[g][d] = s; __syncthreads();
  if (g == 0) atomicAdd(&vm[bh*64 + d], red[0][d]+red[1][d]+red[2][d]+red[3][d]);
}

// ---------------- flash attention v14 ---------------------------------------
// KQK=(KT+1)%4, KST=(KT+3)%4, VPV=KT%4, VST=(KT+2)%4 (KT relative, < brun)
#define AT_BODY(KT, KQK, KST, VPV, VST, STC, STN)                              \
{                                                                              \
  { int k3 = (KT)+3 < brun ? (KT)+3 : brun-1;                                  \
    gload16(kbase + (size_t)(k3*64+sr)*64 + ssc*8, &Ks[KST][tid*8]); }         \
  { int v2 = (KT)+2 < brun ? (KT)+2 : brun-1;                                  \
    gload16(vbase + (size_t)sr*4096 + v2*64 + ssc*8, &Vs[VST][tid*8]); }       \
  asm volatile("s_waitcnt vmcnt(2)" ::: "memory");  /* retire prev K/V */      \
  if ((KT)+1 < brun){                                                          \
    __builtin_amdgcn_s_setprio(1);                                             \
    _Pragma("unroll")                                                          \
    for (int n=0;n<4;n++){                                                     \
      int R = n*16 + l15;                                                      \
      f32x4 a_ = {};                                                           \
      _Pragma("unroll")                                                        \
      for (int kk=0;kk<2;kk++){                                                \
        short8 ka = *(const short8*)&Ks[KQK][R*64 + (((kk<<2)+lg) ^ (R&7))*8]; \
        a_ = mfma16(ka, bq[kk], a_);                                           \
      }                                                                        \
      STN[n] = a_;                                                             \
    }                                                                          \
    __builtin_amdgcn_s_setprio(0);                                             \
  }                                                                            \
  const int base_ = kbase0 + (KT)*64;                                          \
  if (base_ < nv){                       /* body has at least 1 valid key */   \
    float p_[4][4];                                                            \
    if (base_ + 64 <= nv){               /* fully valid (common case) */       \
      _Pragma("unroll")                                                        \
      for (int n=0;n<4;n++)                                                    \
        _Pragma("unroll")                                                      \
        for (int r=0;r<4;r++){                                                 \
          float e_ = __builtin_amdgcn_exp2f(STC[n][r]);                        \
          p_[n][r] = e_; l_run += e_;                                          \
        }                                                                      \
    } else {                             /* straddle body */                   \
      _Pragma("unroll")                                                        \
      for (int n=0;n<4;n++)                                                    \
        _Pragma("unroll")                                                      \
        for (int r=0;r<4;r++){                                                 \
          int ki_ = base_ + n*16 + lg*4 + r;                                   \
          float e_ = (ki_ < nv) ? __builtin_amdgcn_exp2f(STC[n][r]) : 0.f;     \
          p_[n][r] = e_; l_run += e_;                                          \
        }                                                                      \
    }                                                                          \
    _Pragma("unroll")                                                          \
    for (int n=0;n<4;n++){                                                     \
      unsigned p01_, p23_;                                                     \
      asm("v_cvt_pk_bf16_f32 %0, %1, %2" : "=v"(p01_) : "v"(p_[n][0]), "v"(p_[n][1])); \
      asm("v_cvt_pk_bf16_f32 %0, %1, %2" : "=v"(p23_) : "v"(p_[n][2]), "v"(p_[n][3])); \
      int s0_ = n*16 + lg*4;                                                   \
      int off_ = (((s0_>>3) ^ (l15&7))<<3) + (s0_&7);                          \
      *(unsigned*)&Ps[w][l15*64 + off_]     = p01_;                            \
      *(unsigned*)&Ps[w][l15*64 + off_ + 2] = p23_;                            \
    }                                                                          \
    __builtin_amdgcn_s_setprio(1);                                             \
    _Pragma("unroll")                                                          \
    for (int kk=0;kk<2;kk++){                                                  \
      int ch_ = (kk<<2) + lg;                                                  \
      short8 bp_ = *(const short8*)&Ps[w][l15*64 + ((ch_ ^ (l15&7))<<3)];      \
      _Pragma("unroll")                                                        \
      for (int n=0;n<4;n++){                                                   \
        int R = n*16 + l15;                                                    \
        short8 va_ = *(const short8*)&Vs[VPV][R*64 + ((ch_ ^ (R&7))<<3)];      \
        oacc[n] = mfma16(va_, bp_, oacc[n]);                                   \
      }                                                                        \
    }                                                                          \
    __builtin_amdgcn_s_setprio(0);                                             \
  }                                                                            \
  __builtin_amdgcn_s_barrier();                                                \
}

__global__ __launch_bounds__(512) void attn_k(
    const u16* __restrict__ qT, const u16* __restrict__ kc, const u16* __restrict__ vTc,
    const int* __restrict__ nvalid, u16* __restrict__ po, float* __restrict__ pl)
{
  __shared__ __align__(16) u16 Ks[4][64*64];
  __shared__ __align__(16) u16 Vs[4][64*64];
  __shared__ __align__(16) u16 Ps[8][16*64];
  const int qt = blockIdx.x, bh = blockIdx.y, kv = blockIdx.z;
  const int b = bh / 12;
  const int tid = threadIdx.x, w = tid >> 6, l = tid & 63;
  const int l15 = l & 15, lg = l >> 4;
  const int nv = nvalid[b];
  const int bodies = ((nv + 511) & ~511) >> 7;   // per-split tile count (mult of 4)
  const int k0 = kv * bodies;                     // tile offset of this split
  const int kbase0 = k0 * 64;                     // key offset of this split
  // truncate empty tail bodies (wave-uniform), keep multiple of 4
  const int nb_live = (nv - kbase0 + 63) >> 6;    // >0 (nv > npad/2 always)
  const int brun = min(bodies, (nb_live + 3) & ~3);

  short8 bq[2];
  {
    const u16* qp = qT + ((size_t)bh*4096 + qt*128 + w*16 + l15)*64 + lg*8;
    bq[0] = *(const short8*)qp;
    bq[1] = *(const short8*)(qp + 32);
  }
  const u16* kbase = kc + ((size_t)bh*4096 + (size_t)kbase0)*64;
  const u16* vbase = vTc + (size_t)bh*64*4096 + (size_t)kbase0;

  float l_run = 0.f;
  f32x4 oacc[4] = {};   // O^T[d = n*16+lg*4+r][q = l15]

  const int sr = tid >> 3, ssc = (tid & 7) ^ (sr & 7);

  // prologue: stage K0,K1,K2,V0,V1 (relative); drain; QK^T(0)
  gload16(kbase + (size_t)sr*64 + ssc*8,            &Ks[0][tid*8]);
  gload16(kbase + (size_t)(64+sr)*64 + ssc*8,       &Ks[1][tid*8]);
  gload16(kbase + (size_t)(128+sr)*64 + ssc*8,      &Ks[2][tid*8]);
  gload16(vbase + (size_t)sr*4096 + ssc*8,          &Vs[0][tid*8]);
  gload16(vbase + (size_t)sr*4096 + 64 + ssc*8,     &Vs[1][tid*8]);
  asm volatile("s_waitcnt vmcnt(0)" ::: "memory");
  __builtin_amdgcn_s_barrier();

  f32x4 stA[4], stB[4];
  #pragma unroll
  for (int n=0;n<4;n++){
    int R = n*16 + l15;
    f32x4 a_ = {};
    #pragma unroll
    for (int kk=0;kk<2;kk++){
      short8 ka = *(const short8*)&Ks[0][R*64 + (((kk<<2)+lg) ^ (R&7))*8];
      a_ = mfma16(ka, bq[kk], a_);
    }
    stA[n] = a_;
  }
  // Ks[0] first overwritten in body 1 (after body 0's end barrier).

  for (int kt = 0; kt < brun; kt += 4){
    AT_BODY(kt+0, 1, 3, 0, 2, stA, stB)
    AT_BODY(kt+1, 2, 0, 1, 3, stB, stA)
    AT_BODY(kt+2, 3, 1, 2, 0, stA, stB)
    AT_BODY(kt+3, 0, 2, 3, 1, stB, stA)
  }

  // cross-lane l reduction once (sum is linear across bodies)
  l_run += __shfl_xor(l_run, 16);
  l_run += __shfl_xor(l_run, 32);

  // write bf16 O-partials: po[kv][bh][qrow][d]; f32 pl[kv][bh][qrow]
  const int qrow = qt*128 + w*16 + l15;
  u16* pob = po + (((size_t)kv*24 + bh)*4096 + qrow)*64;
  #pragma unroll
  for (int n=0;n<4;n++){
    unsigned q01 = (unsigned)f2b(oacc[n][0]) | ((unsigned)f2b(oacc[n][1]) << 16);
    unsigned q23 = (unsigned)f2b(oacc[n][2]) | ((unsigned)f2b(oacc[n][3]) << 16);
    *(unsigned*)&pob[n*16 + lg*4]     = q01;
    *(unsigned*)&pob[n*16 + lg*4 + 2] = q23;
  }
  if (lg == 0) pl[((size_t)kv*24 + bh)*4096 + qrow] = l_run;
}

// ---------------- combine: o = (O0+O1)/(l0+l1), masked-q -> mean(V) ---------
__global__ __launch_bounds__(256) void comb_k(const u16* __restrict__ po,
    const float* __restrict__ pl, const int* __restrict__ mask,
    const float* __restrict__ vm, u16* __restrict__ o)
{
  int row = blockIdx.x;            // b*4096 + s
  int b = row >> 12, s = row & 4095;
  bool fq = mask[row] != 0;
  int t = threadIdx.x;
  #pragma unroll
  for (int i=0;i<3;i++){
    int j = t + i*256;             // 0..767 = h*64 + d
    int h = j >> 6, d = j & 63;
    size_t pi = (((size_t)b*12 + h)*4096 + s)*64 + d;
    size_t li = ((size_t)b*12 + h)*4096 + s;
    float O = b2f(po[pi]) + b2f(po[(size_t)24*4096*64 + pi]);
    float L = pl[li] + pl[(size_t)24*4096 + li];
    float v = fq ? O / L : vm[(b*12 + h)*64 + d]*(1.f/4096.f);
    o[(size_t)row*768 + j] = f2b(v);
  }
}

// ---------------------------------------------------------------------------
extern "C" void kernel_launch(void* const* d_in, const int* in_sizes, int n_in,
                              void* d_out, int out_size, void* d_ws, size_t ws_size,
                              hipStream_t stream)
{
  const float* x    = (const float*)d_in[0];
  const float* cosb = (const float*)d_in[1];
  const float* sinb = (const float*)d_in[2];
  const float* c    = (const float*)d_in[3];
  const int* amask  = (const int*)d_in[4];
  const float* ln1w = (const float*)d_in[5];
  const float* Wqkv = (const float*)d_in[6];
  const float* Wout = (const float*)d_in[7];
  const float* ln2w = (const float*)d_in[8];
  const float* W1   = (const float*)d_in[9];
  const float* b1   = (const float*)d_in[10];
  const float* W2   = (const float*)d_in[11];
  const float* b2   = (const float*)d_in[12];
  const float* Wada = (const float*)d_in[13];
  const float* bada = (const float*)d_in[14];

  char* ws = (char*)d_ws;
  size_t off = 0;
  auto take = [&](size_t bytes)->char*{
    char* p = ws + off; off = (off + bytes + 255) & ~(size_t)255; return p;
  };
  float* modb = (float*)take(9216*sizeof(float));
  float* vmean= (float*)take(24*64*sizeof(float));
  int*   idx  = (int*)take(8192*sizeof(int));
  int*   nvld = (int*)take(2*sizeof(int));
  u16* hdn  = (u16*)take((size_t)8192*768*2);    // ln1 out; pl aliases; h2 later
  u16* bufA = (u16*)take((size_t)8192*3072*2);   // po aliases; MLP mid later
  u16* vS   = (u16*)take((size_t)8192*768*2);    // v (s-major, RoPE'd)
  u16* qTb  = (u16*)take((size_t)8192*768*2);
  u16* kTb  = (u16*)take((size_t)8192*768*2);    // k (s-major, RoPE'd)
  u16* kc   = (u16*)take((size_t)8192*768*2);    // compacted K rows
  u16* vTc  = (u16*)take((size_t)8192*768*2);    // compacted V, d-major
  u16* ob   = (u16*)take((size_t)8192*768*2);    // attention output (bf16)
  u16* WqkvB= (u16*)take((size_t)2304*768*2);
  u16* WoutB= (u16*)take((size_t)768*768*2);
  u16* W1B  = (u16*)take((size_t)3072*768*2);
  u16* W2B  = (u16*)take((size_t)768*3072*2);
  float* out = (float*)d_out;
  float* x1 = out;                               // reuse d_out for x1 (f32)
  u16*   po = (u16*)bufA;                        // 2*24*4096*64 bf16 = 25.2MB
  float* pl = (float*)hdn;                       // 2*24*4096 f32 = 0.8MB

  cvt4_k<<<6912, 256, 0, stream>>>(Wqkv, WqkvB, Wout, WoutB, W1, W1B, W2, W2B);
  scan_k<<<2, 64, 0, stream>>>(amask, idx, nvld, vmean);

  mod_k  <<<2304, 256, 0, stream>>>(c, Wada, bada, modb);
  ln_mod_k<<<8192, 256, 0, stream>>>(x, hdn, ln1w, modb, 0, 1);
  gemm_k<4><<<dim3(64,18), 256, 0, stream>>>(hdn, WqkvB, nullptr, 8192, 2304, 768,
                                             nullptr, nullptr, nullptr,
                                             cosb, sinb, qTb, kTb, vS);
  gath_k <<<dim3(64,24), 256, 0, stream>>>(kTb, vS, idx, nvld, kc, vTc);
  vmean2_k<<<dim3(16,24), 256, 0, stream>>>(vS, vmean);
  attn_k <<<dim3(32,24,2), 512, 0, stream>>>(qTb, kc, vTc, nvld, po, pl);
  comb_k <<<8192, 256, 0, stream>>>(po, pl, amask, vmean, ob);
  gemm_k<1><<<dim3(64,6), 256, 0, stream>>>(ob, WoutB, x1, 8192, 768, 768,
                                            x, modb, nullptr,
                                            nullptr, nullptr, nullptr, nullptr, nullptr);
  ln_mod_k<<<8192, 256, 0, stream>>>(x1, hdn, ln2w, modb, 3, 4);
  gemm_k<2><<<dim3(64,24), 256, 0, stream>>>(hdn, W1B, bufA, 8192, 3072, 768,
                                             nullptr, nullptr, b1,
                                             nullptr, nullptr, nullptr, nullptr, nullptr);
  gemm_k<3><<<dim3(64,6), 256, 0, stream>>>(bufA, W2B, out, 8192, 768, 3072,
                                            x1, modb, b2,
                                            nullptr, nullptr, nullptr, nullptr, nullptr);
}

// Round 20
// 340.007 us; speedup vs baseline: 1.0531x; 1.0531x over previous
//
#include <hip/hip_runtime.h>
#include <stdint.h>

// f32 I/O, bf16 MFMA internals. r20 = r19 attention/GEMM (byte-identical)
// + launch-count reduction: prep_k = cvt4+scan+mod merged (independent
// ranges), gathv_k = gather+vmean merged, ln_mod_k rewritten wave-per-row
// (no LDS/barriers). Masked-q rows = mean(ALL V) (-1e9 f32 absorption).

typedef unsigned short u16;
typedef __attribute__((ext_vector_type(4))) float f32x4;
typedef __attribute__((ext_vector_type(8))) short short8;
typedef __attribute__((ext_vector_type(4))) short s16x4;
typedef __attribute__((ext_vector_type(8))) __bf16 bf16x8;

__device__ __forceinline__ float b2f(u16 u){
  union { unsigned int i; float f; } v; v.i = ((unsigned int)u) << 16; return v.f;
}
__device__ __forceinline__ u16 f2b(float f){
  union { float f; unsigned int i; } v; v.f = f;
  unsigned int u = v.i;
  u = u + 0x7FFFu + ((u >> 16) & 1u);   // RNE
  return (u16)(u >> 16);
}
__device__ __forceinline__ f32x4 mfma16(short8 a, short8 b, f32x4 c){
  return __builtin_amdgcn_mfma_f32_16x16x32_bf16(
      __builtin_bit_cast(bf16x8, a), __builtin_bit_cast(bf16x8, b), c, 0, 0, 0);
}
__device__ __forceinline__ void gload16(const void* g, void* l){
  void* gnc = const_cast<void*>(g);
  __builtin_amdgcn_global_load_lds((__attribute__((address_space(1))) void*)gnc,
                                   (__attribute__((address_space(3))) void*)l, 16, 0, 0);
}

// ---- prep: weight cvt (blocks 0..6911) | mask scan (6912..6913) | adaLN mod
__global__ __launch_bounds__(256) void prep_k(
    const float* __restrict__ Wqkv, u16* __restrict__ WqkvB,
    const float* __restrict__ Wout, u16* __restrict__ WoutB,
    const float* __restrict__ W1,   u16* __restrict__ W1B,
    const float* __restrict__ W2,   u16* __restrict__ W2B,
    const int* __restrict__ mask, int* __restrict__ idx,
    int* __restrict__ nvalid, float* __restrict__ vm,
    const float* __restrict__ c, const float* __restrict__ Wada,
    const float* __restrict__ bada, float* __restrict__ modb)
{
  const int bid = blockIdx.x;
  if (bid < 6912){
    int i = bid*256 + threadIdx.x;
    const float* src; u16* dst; int j = i;
    if (j < 442368){ src = Wqkv; dst = WqkvB; }
    else if ((j -= 442368) < 147456){ src = Wout; dst = WoutB; }
    else if ((j -= 147456) < 589824){ src = W1; dst = W1B; }
    else { j -= 589824; src = W2; dst = W2B; }
    float4 v = *(const float4*)(src + (size_t)j*4);
    s16x4 o; o[0]=(short)f2b(v.x); o[1]=(short)f2b(v.y);
    o[2]=(short)f2b(v.z); o[3]=(short)f2b(v.w);
    *(s16x4*)(dst + (size_t)j*4) = o;
    return;
  }
  if (bid < 6914){
    if (threadIdx.x >= 64) return;
    int b = bid - 6912, l = threadIdx.x;
    const int* m = mask + b*4096;
    int base = 0;
    for (int i0 = 0; i0 < 4096; i0 += 64){
      int v = m[i0 + l] != 0;
      unsigned long long bal = __ballot(v);
      int pre = __popcll(bal & ((1ull << l) - 1ull));
      if (v) idx[b*4096 + base + pre] = i0 + l;
      base += (int)__popcll(bal);
    }
    if (l == 0) nvalid[b] = base;
    if (b == 0) for (int i = l; i < 24*64; i += 64) vm[i] = 0.f;
    return;
  }
  {
    int o = (bid - 6914)*4 + (threadIdx.x >> 6);   // 0..9215
    int l = threadIdx.x & 63;
    int b = o / 4608, j = o - b*4608;
    const float* cp = c + b*768;
    const float* wp = Wada + (size_t)j*768;
    float s = 0.f;
    for (int k = l; k < 768; k += 64) s += cp[k] * wp[k];
    #pragma unroll
    for (int d=1; d<64; d<<=1) s += __shfl_xor(s, d);
    if (l == 0) modb[o] = s + bada[j];
  }
}

// ---------------- LayerNorm (no affine) * w * (1+scale) + shift -> bf16 -----
// wave-per-row: 4 rows/block, pure shuffle reduce, no LDS/barrier.
__global__ __launch_bounds__(256) void ln_mod_k(const float* __restrict__ xin,
    u16* __restrict__ out, const float* __restrict__ lnw, const float* __restrict__ modb,
    int shift_c, int scale_c)
{
  int row = blockIdx.x*4 + (threadIdx.x >> 6);   // 0..8191
  int l = threadIdx.x & 63;
  int b = row >> 12;
  const float* xp = xin + (size_t)row*768;
  float v[12]; float s = 0.f, s2 = 0.f;
  #pragma unroll
  for (int i=0;i<12;i++){ float f = xp[l + i*64]; v[i] = f; s += f; s2 += f*f; }
  #pragma unroll
  for (int d=1; d<64; d<<=1){ s += __shfl_xor(s, d); s2 += __shfl_xor(s2, d); }
  float mu  = s * (1.f/768.f);
  float var = fmaxf(s2 * (1.f/768.f) - mu*mu, 0.f);
  float rstd = rsqrtf(var + 1e-5f);
  const float* scp = modb + b*4608 + scale_c*768;
  const float* shp = modb + b*4608 + shift_c*768;
  #pragma unroll
  for (int i=0;i<12;i++){
    int d = l + i*64;
    float f = (v[i]-mu)*rstd*lnw[d];
    f = f*(1.f + scp[d]) + shp[d];
    out[(size_t)row*768 + d] = f2b(f);
  }
}

// ---------------- 128x128 BK=64 GEMM, C = A[M,K] @ Bt[N,K]^T, fused epilogues
template<int EPI>
__global__ __launch_bounds__(256) void gemm_k(
    const u16* __restrict__ A, const u16* __restrict__ Bt, void* __restrict__ Cv,
    int M, int N, int K,
    const float* __restrict__ addend, const float* __restrict__ modb,
    const float* __restrict__ bias,
    const float* __restrict__ cosb, const float* __restrict__ sinb,
    u16* __restrict__ qO, u16* __restrict__ kO, u16* __restrict__ vO)
{
  __shared__ __align__(16) u16 As[128*64];
  __shared__ __align__(16) u16 Bs[128*64];
  const int bm = blockIdx.x, bn = blockIdx.y;
  const int tid = threadIdx.x;
  const int w = tid >> 6, l = tid & 63;
  const int wr = w >> 1, wc = w & 1;
  const int l15 = l & 15, lg = l >> 4;
  f32x4 acc[4][4] = {};

  for (int k0 = 0; k0 < K; k0 += 64){
    #pragma unroll
    for (int i=0;i<4;i++){
      int e = i*256 + tid;
      int r = e >> 3, ch = e & 7;
      int sc = ch ^ (r & 7);
      gload16(A  + (size_t)(bm*128 + r)*K + k0 + sc*8, &As[e*8]);
      gload16(Bt + (size_t)(bn*128 + r)*K + k0 + sc*8, &Bs[e*8]);
    }
    __syncthreads();
    #pragma unroll
    for (int kk=0;kk<2;kk++){
      short8 af[4], bfv[4];
      #pragma unroll
      for (int i=0;i<4;i++){
        int ra = wr*64 + i*16 + l15;
        af[i]  = *(const short8*)&As[ra*64 + (((kk*4)+lg) ^ (ra&7))*8];
        int rb = wc*64 + i*16 + l15;
        bfv[i] = *(const short8*)&Bs[rb*64 + (((kk*4)+lg) ^ (rb&7))*8];
      }
      #pragma unroll
      for (int m=0;m<4;m++)
        #pragma unroll
        for (int n=0;n<4;n++)
          acc[m][n] = mfma16(af[m], bfv[n], acc[m][n]);
    }
    __syncthreads();
  }

  if constexpr (EPI == 4){
    const int colseg = bn*128 + wc*64;
    const int qi = colseg / 768;            // 0=q 1=k 2=v
    const int h  = (colseg - qi*768) >> 6;  // 0..11
    const float qs = (qi == 0) ? 0.1803368801111601f : 1.f;  // 0.125*log2(e)
    u16* dst = (qi == 0) ? qO : (qi == 1) ? kO : vO;
    #pragma unroll
    for (int m=0;m<4;m++){
      #pragma unroll
      for (int r=0;r<4;r++){
        int row = bm*128 + wr*64 + m*16 + lg*4 + r;
        int s = row & 4095, bb = row >> 12;
        size_t obase = ((size_t)(bb*12 + h)*4096 + s)*64;
        #pragma unroll
        for (int n2=0;n2<2;n2++){
          int d1 = n2*16 + l15;            // < 32
          int d2 = d1 + 32;
          float c1 = cosb[s*64 + d1], s1 = sinb[s*64 + d1];
          float c2 = cosb[s*64 + d2], s2 = sinb[s*64 + d2];
          float x1 = acc[m][n2][r], x2 = acc[m][n2+2][r];
          dst[obase + d1] = f2b((x1*c1 - x2*s1)*qs);
          dst[obase + d2] = f2b((x2*c2 + x1*s2)*qs);
        }
      }
    }
    return;
  }

  #pragma unroll
  for (int m=0;m<4;m++){
    int row0 = bm*128 + wr*64 + m*16 + lg*4;
    #pragma unroll
    for (int n=0;n<4;n++){
      int col = bn*128 + wc*64 + n*16 + l15;
      #pragma unroll
      for (int r=0;r<4;r++){
        int row = row0 + r;
        size_t idx = (size_t)row*N + col;
        float v = acc[m][n][r];
        if constexpr (EPI == 0){
          ((u16*)Cv)[idx] = f2b(v);
        } else if constexpr (EPI == 1){
          float g = modb[(row>>12)*4608 + 2*768 + col];   // gate_msa
          ((float*)Cv)[idx] = addend[idx] + g*v;
        } else if constexpr (EPI == 2){
          float u = v + bias[col];
          float t0 = 0.7978845608028654f*(u + 0.044715f*u*u*u);
          ((u16*)Cv)[idx] = f2b(0.5f*u*(1.0f + tanhf(t0)));
        } else if constexpr (EPI == 3){
          float g = modb[(row>>12)*4608 + 5*768 + col];   // gate_mlp
          float u = v + bias[col];
          ((float*)Cv)[idx] = addend[idx] + g*u;
        }
      }
    }
  }
}

// ------- gather valid keys (bx<64) | vmean over all V rows (bx>=64) ---------
__global__ __launch_bounds__(256) void gathv_k(const u16* __restrict__ kT,
    const u16* __restrict__ vS, const int* __restrict__ idx,
    const int* __restrict__ nvalid, u16* __restrict__ kc, u16* __restrict__ vTc,
    float* __restrict__ vm)
{
  int bh = blockIdx.y;
  int t = threadIdx.x;
  if (blockIdx.x >= 64){
    // vmean part: 16 blocks x 256 rows
    int r0 = (blockIdx.x - 64)*256;
    int d = t & 63, g = t >> 6;
    const u16* p = vS + ((size_t)bh*4096 + r0)*64 + d;
    float s = 0.f;
    for (int k = g; k < 256; k += 4) s += b2f(p[(size_t)k*64]);
    __shared__ float red[4][64];
    red[g][d] = s; __syncthreads();
    if (g == 0) atomicAdd(&vm[bh*64 + d], red[0][d]+red[1][d]+red[2][d]+red[3][d]);
    return;
  }
  __shared__ __align__(16) u16 tile[64][72];
  int j0 = blockIdx.x*64;
  int b = bh / 12;
  int nv = nvalid[b];
  int npad = (nv + 511) & ~511;
  if (j0 >= npad) return;
  #pragma unroll
  for (int i=0;i<2;i++){
    int e = i*256 + t;
    int r = e >> 3, ch = e & 7;
    int j = j0 + r;
    short8 kv8 = {}, vv8 = {};
    if (j < nv){
      int src = idx[b*4096 + j];
      kv8 = *(const short8*)(kT + ((size_t)bh*4096 + src)*64 + ch*8);
      vv8 = *(const short8*)(vS + ((size_t)bh*4096 + src)*64 + ch*8);
    }
    *(short8*)(kc + ((size_t)bh*4096 + j)*64 + ch*8) = kv8;
    *(short8*)&tile[r][ch*8] = vv8;
  }
  __syncthreads();
  #pragma unroll
  for (int i=0;i<2;i++){
    int e = i*256 + t;
    int dd = e >> 3, s0 = (e & 7)*8;
    short8 ov;
    #pragma unroll
    for (int k2=0;k2<8;k2++) ov[k2] = (short)tile[s0+k2][dd];
    *(short8*)(vTc + ((size_t)bh*64 + dd)*4096 + j0 + s0) = ov;
  }
}

// ---------------- flash attention (r19, known good) -------------------------
// KQK=(KT+1)%4, KST=(KT+3)%4, VPV=KT%4, VST=(KT+2)%4 (KT relative, < brun)
#define AT_BODY(KT, KQK, KST, VPV, VST, STC, STN)                              \
{                                                                              \
  { int k3 = (KT)+3 < brun ? (KT)+3 : brun-1;                                  \
    gload16(kbase + (size_t)(k3*64+sr)*64 + ssc*8, &Ks[KST][tid*8]); }         \
  { int v2 = (KT)+2 < brun ? (KT)+2 : brun-1;                                  \
    gload16(vbase + (size_t)sr*4096 + v2*64 + ssc*8, &Vs[VST][tid*8]); }       \
  asm volatile("s_waitcnt vmcnt(2)" ::: "memory");  /* retire prev K/V */      \
  if ((KT)+1 < brun){                                                          \
    __builtin_amdgcn_s_setprio(1);                                             \
    _Pragma("unroll")                                                          \
    for (int n=0;n<4;n++){                                                     \
      int R = n*16 + l15;                                                      \
      f32x4 a_ = {};                                                           \
      _Pragma("unroll")                                                        \
      for (int kk=0;kk<2;kk++){                                                \
        short8 ka = *(const short8*)&Ks[KQK][R*64 + (((kk<<2)+lg) ^ (R&7))*8]; \
        a_ = mfma16(ka, bq[kk], a_);                                           \
      }                                                                        \
      STN[n] = a_;                                                             \
    }                                                                          \
    __builtin_amdgcn_s_setprio(0);                                             \
  }                                                                            \
  const int base_ = kbase0 + (KT)*64;                                          \
  if (base_ < nv){                       /* body has at least 1 valid key */   \
    float p_[4][4];                                                            \
    if (base_ + 64 <= nv){               /* fully valid (common case) */       \
      _Pragma("unroll")                                                        \
      for (int n=0;n<4;n++)                                                    \
        _Pragma("unroll")                                                      \
        for (int r=0;r<4;r++){                                                 \
          float e_ = __builtin_amdgcn_exp2f(STC[n][r]);                        \
          p_[n][r] = e_; l_run += e_;                                          \
        }                                                                      \
    } else {                             /* straddle body */                   \
      _Pragma("unroll")                                                        \
      for (int n=0;n<4;n++)                                                    \
        _Pragma("unroll")                                                      \
        for (int r=0;r<4;r++){                                                 \
          int ki_ = base_ + n*16 + lg*4 + r;                                   \
          float e_ = (ki_ < nv) ? __builtin_amdgcn_exp2f(STC[n][r]) : 0.f;     \
          p_[n][r] = e_; l_run += e_;                                          \
        }                                                                      \
    }                                                                          \
    _Pragma("unroll")                                                          \
    for (int n=0;n<4;n++){                                                     \
      unsigned p01_, p23_;                                                     \
      asm("v_cvt_pk_bf16_f32 %0, %1, %2" : "=v"(p01_) : "v"(p_[n][0]), "v"(p_[n][1])); \
      asm("v_cvt_pk_bf16_f32 %0, %1, %2" : "=v"(p23_) : "v"(p_[n][2]), "v"(p_[n][3])); \
      int s0_ = n*16 + lg*4;                                                   \
      int off_ = (((s0_>>3) ^ (l15&7))<<3) + (s0_&7);                          \
      *(unsigned*)&Ps[w][l15*64 + off_]     = p01_;                            \
      *(unsigned*)&Ps[w][l15*64 + off_ + 2] = p23_;                            \
    }                                                                          \
    __builtin_amdgcn_s_setprio(1);                                             \
    _Pragma("unroll")                                                          \
    for (int kk=0;kk<2;kk++){                                                  \
      int ch_ = (kk<<2) + lg;                                                  \
      short8 bp_ = *(const short8*)&Ps[w][l15*64 + ((ch_ ^ (l15&7))<<3)];      \
      _Pragma("unroll")                                                        \
      for (int n=0;n<4;n++){                                                   \
        int R = n*16 + l15;                                                    \
        short8 va_ = *(const short8*)&Vs[VPV][R*64 + ((ch_ ^ (R&7))<<3)];      \
        oacc[n] = mfma16(va_, bp_, oacc[n]);                                   \
      }                                                                        \
    }                                                                          \
    __builtin_amdgcn_s_setprio(0);                                             \
  }                                                                            \
  __builtin_amdgcn_s_barrier();                                                \
}

__global__ __launch_bounds__(512) void attn_k(
    const u16* __restrict__ qT, const u16* __restrict__ kc, const u16* __restrict__ vTc,
    const int* __restrict__ nvalid, u16* __restrict__ po, float* __restrict__ pl)
{
  __shared__ __align__(16) u16 Ks[4][64*64];
  __shared__ __align__(16) u16 Vs[4][64*64];
  __shared__ __align__(16) u16 Ps[8][16*64];
  const int qt = blockIdx.x, bh = blockIdx.y, kv = blockIdx.z;
  const int b = bh / 12;
  const int tid = threadIdx.x, w = tid >> 6, l = tid & 63;
  const int l15 = l & 15, lg = l >> 4;
  const int nv = nvalid[b];
  const int bodies = ((nv + 511) & ~511) >> 7;   // per-split tile count (mult of 4)
  const int k0 = kv * bodies;                     // tile offset of this split
  const int kbase0 = k0 * 64;                     // key offset of this split
  const int nb_live = (nv - kbase0 + 63) >> 6;
  const int brun = min(bodies, (nb_live + 3) & ~3);

  short8 bq[2];
  {
    const u16* qp = qT + ((size_t)bh*4096 + qt*128 + w*16 + l15)*64 + lg*8;
    bq[0] = *(const short8*)qp;
    bq[1] = *(const short8*)(qp + 32);
  }
  const u16* kbase = kc + ((size_t)bh*4096 + (size_t)kbase0)*64;
  const u16* vbase = vTc + (size_t)bh*64*4096 + (size_t)kbase0;

  float l_run = 0.f;
  f32x4 oacc[4] = {};   // O^T[d = n*16+lg*4+r][q = l15]

  const int sr = tid >> 3, ssc = (tid & 7) ^ (sr & 7);

  // prologue: stage K0,K1,K2,V0,V1 (relative); drain; QK^T(0)
  gload16(kbase + (size_t)sr*64 + ssc*8,            &Ks[0][tid*8]);
  gload16(kbase + (size_t)(64+sr)*64 + ssc*8,       &Ks[1][tid*8]);
  gload16(kbase + (size_t)(128+sr)*64 + ssc*8,      &Ks[2][tid*8]);
  gload16(vbase + (size_t)sr*4096 + ssc*8,          &Vs[0][tid*8]);
  gload16(vbase + (size_t)sr*4096 + 64 + ssc*8,     &Vs[1][tid*8]);
  asm volatile("s_waitcnt vmcnt(0)" ::: "memory");
  __builtin_amdgcn_s_barrier();

  f32x4 stA[4], stB[4];
  #pragma unroll
  for (int n=0;n<4;n++){
    int R = n*16 + l15;
    f32x4 a_ = {};
    #pragma unroll
    for (int kk=0;kk<2;kk++){
      short8 ka = *(const short8*)&Ks[0][R*64 + (((kk<<2)+lg) ^ (R&7))*8];
      a_ = mfma16(ka, bq[kk], a_);
    }
    stA[n] = a_;
  }
  // Ks[0] first overwritten in body 1 (after body 0's end barrier).

  for (int kt = 0; kt < brun; kt += 4){
    AT_BODY(kt+0, 1, 3, 0, 2, stA, stB)
    AT_BODY(kt+1, 2, 0, 1, 3, stB, stA)
    AT_BODY(kt+2, 3, 1, 2, 0, stA, stB)
    AT_BODY(kt+3, 0, 2, 3, 1, stB, stA)
  }

  // cross-lane l reduction once (sum is linear across bodies)
  l_run += __shfl_xor(l_run, 16);
  l_run += __shfl_xor(l_run, 32);

  // write bf16 O-partials: po[kv][bh][qrow][d]; f32 pl[kv][bh][qrow]
  const int qrow = qt*128 + w*16 + l15;
  u16* pob = po + (((size_t)kv*24 + bh)*4096 + qrow)*64;
  #pragma unroll
  for (int n=0;n<4;n++){
    unsigned q01 = (unsigned)f2b(oacc[n][0]) | ((unsigned)f2b(oacc[n][1]) << 16);
    unsigned q23 = (unsigned)f2b(oacc[n][2]) | ((unsigned)f2b(oacc[n][3]) << 16);
    *(unsigned*)&pob[n*16 + lg*4]     = q01;
    *(unsigned*)&pob[n*16 + lg*4 + 2] = q23;
  }
  if (lg == 0) pl[((size_t)kv*24 + bh)*4096 + qrow] = l_run;
}

// ---------------- combine: o = (O0+O1)/(l0+l1), masked-q -> mean(V) ---------
__global__ __launch_bounds__(256) void comb_k(const u16* __restrict__ po,
    const float* __restrict__ pl, const int* __restrict__ mask,
    const float* __restrict__ vm, u16* __restrict__ o)
{
  int row = blockIdx.x;            // b*4096 + s
  int b = row >> 12, s = row & 4095;
  bool fq = mask[row] != 0;
  int t = threadIdx.x;
  #pragma unroll
  for (int i=0;i<3;i++){
    int j = t + i*256;             // 0..767 = h*64 + d
    int h = j >> 6, d = j & 63;
    size_t pi = (((size_t)b*12 + h)*4096 + s)*64 + d;
    size_t li = ((size_t)b*12 + h)*4096 + s;
    float O = b2f(po[pi]) + b2f(po[(size_t)24*4096*64 + pi]);
    float L = pl[li] + pl[(size_t)24*4096 + li];
    float v = fq ? O / L : vm[(b*12 + h)*64 + d]*(1.f/4096.f);
    o[(size_t)row*768 + j] = f2b(v);
  }
}

// ---------------------------------------------------------------------------
extern "C" void kernel_launch(void* const* d_in, const int* in_sizes, int n_in,
                              void* d_out, int out_size, void* d_ws, size_t ws_size,
                              hipStream_t stream)
{
  const float* x    = (const float*)d_in[0];
  const float* cosb = (const float*)d_in[1];
  const float* sinb = (const float*)d_in[2];
  const float* c    = (const float*)d_in[3];
  const int* amask  = (const int*)d_in[4];
  const float* ln1w = (const float*)d_in[5];
  const float* Wqkv = (const float*)d_in[6];
  const float* Wout = (const float*)d_in[7];
  const float* ln2w = (const float*)d_in[8];
  const float* W1   = (const float*)d_in[9];
  const float* b1   = (const float*)d_in[10];
  const float* W2   = (const float*)d_in[11];
  const float* b2   = (const float*)d_in[12];
  const float* Wada = (const float*)d_in[13];
  const float* bada = (const float*)d_in[14];

  char* ws = (char*)d_ws;
  size_t off = 0;
  auto take = [&](size_t bytes)->char*{
    char* p = ws + off; off = (off + bytes + 255) & ~(size_t)255; return p;
  };
  float* modb = (float*)take(9216*sizeof(float));
  float* vmean= (float*)take(24*64*sizeof(float));
  int*   idx  = (int*)take(8192*sizeof(int));
  int*   nvld = (int*)take(2*sizeof(int));
  u16* hdn  = (u16*)take((size_t)8192*768*2);    // ln1 out; pl aliases; h2 later
  u16* bufA = (u16*)take((size_t)8192*3072*2);   // po aliases; MLP mid later
  u16* vS   = (u16*)take((size_t)8192*768*2);    // v (s-major, RoPE'd)
  u16* qTb  = (u16*)take((size_t)8192*768*2);
  u16* kTb  = (u16*)take((size_t)8192*768*2);    // k (s-major, RoPE'd)
  u16* kc   = (u16*)take((size_t)8192*768*2);    // compacted K rows
  u16* vTc  = (u16*)take((size_t)8192*768*2);    // compacted V, d-major
  u16* ob   = (u16*)take((size_t)8192*768*2);    // attention output (bf16)
  u16* WqkvB= (u16*)take((size_t)2304*768*2);
  u16* WoutB= (u16*)take((size_t)768*768*2);
  u16* W1B  = (u16*)take((size_t)3072*768*2);
  u16* W2B  = (u16*)take((size_t)768*3072*2);
  float* out = (float*)d_out;
  float* x1 = out;                               // reuse d_out for x1 (f32)
  u16*   po = (u16*)bufA;                        // 2*24*4096*64 bf16 = 25.2MB
  float* pl = (float*)hdn;                       // 2*24*4096 f32 = 0.8MB

  prep_k<<<9218, 256, 0, stream>>>(Wqkv, WqkvB, Wout, WoutB, W1, W1B, W2, W2B,
                                   amask, idx, nvld, vmean, c, Wada, bada, modb);
  ln_mod_k<<<2048, 256, 0, stream>>>(x, hdn, ln1w, modb, 0, 1);
  gemm_k<4><<<dim3(64,18), 256, 0, stream>>>(hdn, WqkvB, nullptr, 8192, 2304, 768,
                                             nullptr, nullptr, nullptr,
                                             cosb, sinb, qTb, kTb, vS);
  gathv_k<<<dim3(80,24), 256, 0, stream>>>(kTb, vS, idx, nvld, kc, vTc, vmean);
  attn_k <<<dim3(32,24,2), 512, 0, stream>>>(qTb, kc, vTc, nvld, po, pl);
  comb_k <<<8192, 256, 0, stream>>>(po, pl, amask, vmean, ob);
  gemm_k<1><<<dim3(64,6), 256, 0, stream>>>(ob, WoutB, x1, 8192, 768, 768,
                                            x, modb, nullptr,
                                            nullptr, nullptr, nullptr, nullptr, nullptr);
  ln_mod_k<<<2048, 256, 0, stream>>>(x1, hdn, ln2w, modb, 3, 4);
  gemm_k<2><<<dim3(64,24), 256, 0, stream>>>(hdn, W1B, bufA, 8192, 3072, 768,
                                             nullptr, nullptr, b1,
                                             nullptr, nullptr, nullptr, nullptr, nullptr);
  gemm_k<3><<<dim3(64,6), 256, 0, stream>>>(bufA, W2B, out, 8192, 768, 3072,
                                            x1, modb, b2,
                                            nullptr, nullptr, nullptr, nullptr, nullptr);
}

// Round 21
// 339.002 us; speedup vs baseline: 1.0562x; 1.0030x over previous
//
#include <hip/hip_runtime.h>
#include <stdint.h>

// f32 I/O, bf16 MFMA internals. r21 = r20 with BALANCED KV-split: split the
// LIVE tile count bl=ceil(nv/64) at round4(bl/2) instead of splitting the
// padded range (was 20/12 live bodies at nv~2048; now 16/16). Partials stay
// disjoint + exactly combinable. Masked-q rows = mean(ALL V).

typedef unsigned short u16;
typedef __attribute__((ext_vector_type(4))) float f32x4;
typedef __attribute__((ext_vector_type(8))) short short8;
typedef __attribute__((ext_vector_type(4))) short s16x4;
typedef __attribute__((ext_vector_type(8))) __bf16 bf16x8;

__device__ __forceinline__ float b2f(u16 u){
  union { unsigned int i; float f; } v; v.i = ((unsigned int)u) << 16; return v.f;
}
__device__ __forceinline__ u16 f2b(float f){
  union { float f; unsigned int i; } v; v.f = f;
  unsigned int u = v.i;
  u = u + 0x7FFFu + ((u >> 16) & 1u);   // RNE
  return (u16)(u >> 16);
}
__device__ __forceinline__ f32x4 mfma16(short8 a, short8 b, f32x4 c){
  return __builtin_amdgcn_mfma_f32_16x16x32_bf16(
      __builtin_bit_cast(bf16x8, a), __builtin_bit_cast(bf16x8, b), c, 0, 0, 0);
}
__device__ __forceinline__ void gload16(const void* g, void* l){
  void* gnc = const_cast<void*>(g);
  __builtin_amdgcn_global_load_lds((__attribute__((address_space(1))) void*)gnc,
                                   (__attribute__((address_space(3))) void*)l, 16, 0, 0);
}

// ---- prep: weight cvt (blocks 0..6911) | mask scan (6912..6913) | adaLN mod
__global__ __launch_bounds__(256) void prep_k(
    const float* __restrict__ Wqkv, u16* __restrict__ WqkvB,
    const float* __restrict__ Wout, u16* __restrict__ WoutB,
    const float* __restrict__ W1,   u16* __restrict__ W1B,
    const float* __restrict__ W2,   u16* __restrict__ W2B,
    const int* __restrict__ mask, int* __restrict__ idx,
    int* __restrict__ nvalid, float* __restrict__ vm,
    const float* __restrict__ c, const float* __restrict__ Wada,
    const float* __restrict__ bada, float* __restrict__ modb)
{
  const int bid = blockIdx.x;
  if (bid < 6912){
    int i = bid*256 + threadIdx.x;
    const float* src; u16* dst; int j = i;
    if (j < 442368){ src = Wqkv; dst = WqkvB; }
    else if ((j -= 442368) < 147456){ src = Wout; dst = WoutB; }
    else if ((j -= 147456) < 589824){ src = W1; dst = W1B; }
    else { j -= 589824; src = W2; dst = W2B; }
    float4 v = *(const float4*)(src + (size_t)j*4);
    s16x4 o; o[0]=(short)f2b(v.x); o[1]=(short)f2b(v.y);
    o[2]=(short)f2b(v.z); o[3]=(short)f2b(v.w);
    *(s16x4*)(dst + (size_t)j*4) = o;
    return;
  }
  if (bid < 6914){
    if (threadIdx.x >= 64) return;
    int b = bid - 6912, l = threadIdx.x;
    const int* m = mask + b*4096;
    int base = 0;
    for (int i0 = 0; i0 < 4096; i0 += 64){
      int v = m[i0 + l] != 0;
      unsigned long long bal = __ballot(v);
      int pre = __popcll(bal & ((1ull << l) - 1ull));
      if (v) idx[b*4096 + base + pre] = i0 + l;
      base += (int)__popcll(bal);
    }
    if (l == 0) nvalid[b] = base;
    if (b == 0) for (int i = l; i < 24*64; i += 64) vm[i] = 0.f;
    return;
  }
  {
    int o = (bid - 6914)*4 + (threadIdx.x >> 6);   // 0..9215
    int l = threadIdx.x & 63;
    int b = o / 4608, j = o - b*4608;
    const float* cp = c + b*768;
    const float* wp = Wada + (size_t)j*768;
    float s = 0.f;
    for (int k = l; k < 768; k += 64) s += cp[k] * wp[k];
    #pragma unroll
    for (int d=1; d<64; d<<=1) s += __shfl_xor(s, d);
    if (l == 0) modb[o] = s + bada[j];
  }
}

// ---------------- LayerNorm (no affine) * w * (1+scale) + shift -> bf16 -----
// wave-per-row: 4 rows/block, pure shuffle reduce, no LDS/barrier.
__global__ __launch_bounds__(256) void ln_mod_k(const float* __restrict__ xin,
    u16* __restrict__ out, const float* __restrict__ lnw, const float* __restrict__ modb,
    int shift_c, int scale_c)
{
  int row = blockIdx.x*4 + (threadIdx.x >> 6);   // 0..8191
  int l = threadIdx.x & 63;
  int b = row >> 12;
  const float* xp = xin + (size_t)row*768;
  float v[12]; float s = 0.f, s2 = 0.f;
  #pragma unroll
  for (int i=0;i<12;i++){ float f = xp[l + i*64]; v[i] = f; s += f; s2 += f*f; }
  #pragma unroll
  for (int d=1; d<64; d<<=1){ s += __shfl_xor(s, d); s2 += __shfl_xor(s2, d); }
  float mu  = s * (1.f/768.f);
  float var = fmaxf(s2 * (1.f/768.f) - mu*mu, 0.f);
  float rstd = rsqrtf(var + 1e-5f);
  const float* scp = modb + b*4608 + scale_c*768;
  const float* shp = modb + b*4608 + shift_c*768;
  #pragma unroll
  for (int i=0;i<12;i++){
    int d = l + i*64;
    float f = (v[i]-mu)*rstd*lnw[d];
    f = f*(1.f + scp[d]) + shp[d];
    out[(size_t)row*768 + d] = f2b(f);
  }
}

// ---------------- 128x128 BK=64 GEMM, C = A[M,K] @ Bt[N,K]^T, fused epilogues
template<int EPI>
__global__ __launch_bounds__(256) void gemm_k(
    const u16* __restrict__ A, const u16* __restrict__ Bt, void* __restrict__ Cv,
    int M, int N, int K,
    const float* __restrict__ addend, const float* __restrict__ modb,
    const float* __restrict__ bias,
    const float* __restrict__ cosb, const float* __restrict__ sinb,
    u16* __restrict__ qO, u16* __restrict__ kO, u16* __restrict__ vO)
{
  __shared__ __align__(16) u16 As[128*64];
  __shared__ __align__(16) u16 Bs[128*64];
  const int bm = blockIdx.x, bn = blockIdx.y;
  const int tid = threadIdx.x;
  const int w = tid >> 6, l = tid & 63;
  const int wr = w >> 1, wc = w & 1;
  const int l15 = l & 15, lg = l >> 4;
  f32x4 acc[4][4] = {};

  for (int k0 = 0; k0 < K; k0 += 64){
    #pragma unroll
    for (int i=0;i<4;i++){
      int e = i*256 + tid;
      int r = e >> 3, ch = e & 7;
      int sc = ch ^ (r & 7);
      gload16(A  + (size_t)(bm*128 + r)*K + k0 + sc*8, &As[e*8]);
      gload16(Bt + (size_t)(bn*128 + r)*K + k0 + sc*8, &Bs[e*8]);
    }
    __syncthreads();
    #pragma unroll
    for (int kk=0;kk<2;kk++){
      short8 af[4], bfv[4];
      #pragma unroll
      for (int i=0;i<4;i++){
        int ra = wr*64 + i*16 + l15;
        af[i]  = *(const short8*)&As[ra*64 + (((kk*4)+lg) ^ (ra&7))*8];
        int rb = wc*64 + i*16 + l15;
        bfv[i] = *(const short8*)&Bs[rb*64 + (((kk*4)+lg) ^ (rb&7))*8];
      }
      #pragma unroll
      for (int m=0;m<4;m++)
        #pragma unroll
        for (int n=0;n<4;n++)
          acc[m][n] = mfma16(af[m], bfv[n], acc[m][n]);
    }
    __syncthreads();
  }

  if constexpr (EPI == 4){
    const int colseg = bn*128 + wc*64;
    const int qi = colseg / 768;            // 0=q 1=k 2=v
    const int h  = (colseg - qi*768) >> 6;  // 0..11
    const float qs = (qi == 0) ? 0.1803368801111601f : 1.f;  // 0.125*log2(e)
    u16* dst = (qi == 0) ? qO : (qi == 1) ? kO : vO;
    #pragma unroll
    for (int m=0;m<4;m++){
      #pragma unroll
      for (int r=0;r<4;r++){
        int row = bm*128 + wr*64 + m*16 + lg*4 + r;
        int s = row & 4095, bb = row >> 12;
        size_t obase = ((size_t)(bb*12 + h)*4096 + s)*64;
        #pragma unroll
        for (int n2=0;n2<2;n2++){
          int d1 = n2*16 + l15;            // < 32
          int d2 = d1 + 32;
          float c1 = cosb[s*64 + d1], s1 = sinb[s*64 + d1];
          float c2 = cosb[s*64 + d2], s2 = sinb[s*64 + d2];
          float x1 = acc[m][n2][r], x2 = acc[m][n2+2][r];
          dst[obase + d1] = f2b((x1*c1 - x2*s1)*qs);
          dst[obase + d2] = f2b((x2*c2 + x1*s2)*qs);
        }
      }
    }
    return;
  }

  #pragma unroll
  for (int m=0;m<4;m++){
    int row0 = bm*128 + wr*64 + m*16 + lg*4;
    #pragma unroll
    for (int n=0;n<4;n++){
      int col = bn*128 + wc*64 + n*16 + l15;
      #pragma unroll
      for (int r=0;r<4;r++){
        int row = row0 + r;
        size_t idx = (size_t)row*N + col;
        float v = acc[m][n][r];
        if constexpr (EPI == 0){
          ((u16*)Cv)[idx] = f2b(v);
        } else if constexpr (EPI == 1){
          float g = modb[(row>>12)*4608 + 2*768 + col];   // gate_msa
          ((float*)Cv)[idx] = addend[idx] + g*v;
        } else if constexpr (EPI == 2){
          float u = v + bias[col];
          float t0 = 0.7978845608028654f*(u + 0.044715f*u*u*u);
          ((u16*)Cv)[idx] = f2b(0.5f*u*(1.0f + tanhf(t0)));
        } else if constexpr (EPI == 3){
          float g = modb[(row>>12)*4608 + 5*768 + col];   // gate_mlp
          float u = v + bias[col];
          ((float*)Cv)[idx] = addend[idx] + g*u;
        }
      }
    }
  }
}

// ------- gather valid keys (bx<64) | vmean over all V rows (bx>=64) ---------
__global__ __launch_bounds__(256) void gathv_k(const u16* __restrict__ kT,
    const u16* __restrict__ vS, const int* __restrict__ idx,
    const int* __restrict__ nvalid, u16* __restrict__ kc, u16* __restrict__ vTc,
    float* __restrict__ vm)
{
  int bh = blockIdx.y;
  int t = threadIdx.x;
  if (blockIdx.x >= 64){
    int r0 = (blockIdx.x - 64)*256;
    int d = t & 63, g = t >> 6;
    const u16* p = vS + ((size_t)bh*4096 + r0)*64 + d;
    float s = 0.f;
    for (int k = g; k < 256; k += 4) s += b2f(p[(size_t)k*64]);
    __shared__ float red[4][64];
    red[g][d] = s; __syncthreads();
    if (g == 0) atomicAdd(&vm[bh*64 + d], red[0][d]+red[1][d]+red[2][d]+red[3][d]);
    return;
  }
  __shared__ __align__(16) u16 tile[64][72];
  int j0 = blockIdx.x*64;
  int b = bh / 12;
  int nv = nvalid[b];
  int npad = (nv + 511) & ~511;
  if (j0 >= npad) return;
  #pragma unroll
  for (int i=0;i<2;i++){
    int e = i*256 + t;
    int r = e >> 3, ch = e & 7;
    int j = j0 + r;
    short8 kv8 = {}, vv8 = {};
    if (j < nv){
      int src = idx[b*4096 + j];
      kv8 = *(const short8*)(kT + ((size_t)bh*4096 + src)*64 + ch*8);
      vv8 = *(const short8*)(vS + ((size_t)bh*4096 + src)*64 + ch*8);
    }
    *(short8*)(kc + ((size_t)bh*4096 + j)*64 + ch*8) = kv8;
    *(short8*)&tile[r][ch*8] = vv8;
  }
  __syncthreads();
  #pragma unroll
  for (int i=0;i<2;i++){
    int e = i*256 + t;
    int dd = e >> 3, s0 = (e & 7)*8;
    short8 ov;
    #pragma unroll
    for (int k2=0;k2<8;k2++) ov[k2] = (short)tile[s0+k2][dd];
    *(short8*)(vTc + ((size_t)bh*64 + dd)*4096 + j0 + s0) = ov;
  }
}

// ---------------- flash attention (r19 body, balanced split) ----------------
// KQK=(KT+1)%4, KST=(KT+3)%4, VPV=KT%4, VST=(KT+2)%4 (KT relative, < brun)
#define AT_BODY(KT, KQK, KST, VPV, VST, STC, STN)                              \
{                                                                              \
  { int k3 = (KT)+3 < brun ? (KT)+3 : brun-1;                                  \
    gload16(kbase + (size_t)(k3*64+sr)*64 + ssc*8, &Ks[KST][tid*8]); }         \
  { int v2 = (KT)+2 < brun ? (KT)+2 : brun-1;                                  \
    gload16(vbase + (size_t)sr*4096 + v2*64 + ssc*8, &Vs[VST][tid*8]); }       \
  asm volatile("s_waitcnt vmcnt(2)" ::: "memory");  /* retire prev K/V */      \
  if ((KT)+1 < brun){                                                          \
    __builtin_amdgcn_s_setprio(1);                                             \
    _Pragma("unroll")                                                          \
    for (int n=0;n<4;n++){                                                     \
      int R = n*16 + l15;                                                      \
      f32x4 a_ = {};                                                           \
      _Pragma("unroll")                                                        \
      for (int kk=0;kk<2;kk++){                                                \
        short8 ka = *(const short8*)&Ks[KQK][R*64 + (((kk<<2)+lg) ^ (R&7))*8]; \
        a_ = mfma16(ka, bq[kk], a_);                                           \
      }                                                                        \
      STN[n] = a_;                                                             \
    }                                                                          \
    __builtin_amdgcn_s_setprio(0);                                             \
  }                                                                            \
  const int base_ = kbase0 + (KT)*64;                                          \
  if (base_ < nv){                       /* body has at least 1 valid key */   \
    float p_[4][4];                                                            \
    if (base_ + 64 <= nv){               /* fully valid (common case) */       \
      _Pragma("unroll")                                                        \
      for (int n=0;n<4;n++)                                                    \
        _Pragma("unroll")                                                      \
        for (int r=0;r<4;r++){                                                 \
          float e_ = __builtin_amdgcn_exp2f(STC[n][r]);                        \
          p_[n][r] = e_; l_run += e_;                                          \
        }                                                                      \
    } else {                             /* straddle body */                   \
      _Pragma("unroll")                                                        \
      for (int n=0;n<4;n++)                                                    \
        _Pragma("unroll")                                                      \
        for (int r=0;r<4;r++){                                                 \
          int ki_ = base_ + n*16 + lg*4 + r;                                   \
          float e_ = (ki_ < nv) ? __builtin_amdgcn_exp2f(STC[n][r]) : 0.f;     \
          p_[n][r] = e_; l_run += e_;                                          \
        }                                                                      \
    }                                                                          \
    _Pragma("unroll")                                                          \
    for (int n=0;n<4;n++){                                                     \
      unsigned p01_, p23_;                                                     \
      asm("v_cvt_pk_bf16_f32 %0, %1, %2" : "=v"(p01_) : "v"(p_[n][0]), "v"(p_[n][1])); \
      asm("v_cvt_pk_bf16_f32 %0, %1, %2" : "=v"(p23_) : "v"(p_[n][2]), "v"(p_[n][3])); \
      int s0_ = n*16 + lg*4;                                                   \
      int off_ = (((s0_>>3) ^ (l15&7))<<3) + (s0_&7);                          \
      *(unsigned*)&Ps[w][l15*64 + off_]     = p01_;                            \
      *(unsigned*)&Ps[w][l15*64 + off_ + 2] = p23_;                            \
    }                                                                          \
    __builtin_amdgcn_s_setprio(1);                                             \
    _Pragma("unroll")                                                          \
    for (int kk=0;kk<2;kk++){                                                  \
      int ch_ = (kk<<2) + lg;                                                  \
      short8 bp_ = *(const short8*)&Ps[w][l15*64 + ((ch_ ^ (l15&7))<<3)];      \
      _Pragma("unroll")                                                        \
      for (int n=0;n<4;n++){                                                   \
        int R = n*16 + l15;                                                    \
        short8 va_ = *(const short8*)&Vs[VPV][R*64 + ((ch_ ^ (R&7))<<3)];      \
        oacc[n] = mfma16(va_, bp_, oacc[n]);                                   \
      }                                                                        \
    }                                                                          \
    __builtin_amdgcn_s_setprio(0);                                             \
  }                                                                            \
  __builtin_amdgcn_s_barrier();                                                \
}

__global__ __launch_bounds__(512) void attn_k(
    const u16* __restrict__ qT, const u16* __restrict__ kc, const u16* __restrict__ vTc,
    const int* __restrict__ nvalid, u16* __restrict__ po, float* __restrict__ pl)
{
  __shared__ __align__(16) u16 Ks[4][64*64];
  __shared__ __align__(16) u16 Vs[4][64*64];
  __shared__ __align__(16) u16 Ps[8][16*64];
  const int qt = blockIdx.x, bh = blockIdx.y, kv = blockIdx.z;
  const int b = bh / 12;
  const int tid = threadIdx.x, w = tid >> 6, l = tid & 63;
  const int l15 = l & 15, lg = l >> 4;
  const int nv = nvalid[b];
  // balanced split over LIVE tiles: bl = ceil(nv/64); split-0 gets
  // b0 = round4(ceil(bl/2)), split-1 the rest (round4). Pad tiles (zeros,
  // skipped by base_<nv) cover any overrun; npad tiles >= bl+7.
  const int bl = (nv + 63) >> 6;
  const int b0 = (((bl + 1) >> 1) + 3) & ~3;
  const int k0 = kv ? b0 : 0;
  const int kbase0 = k0 * 64;
  const int brun = kv ? ((bl - b0 + 3) & ~3) : b0;

  short8 bq[2];
  {
    const u16* qp = qT + ((size_t)bh*4096 + qt*128 + w*16 + l15)*64 + lg*8;
    bq[0] = *(const short8*)qp;
    bq[1] = *(const short8*)(qp + 32);
  }
  const u16* kbase = kc + ((size_t)bh*4096 + (size_t)kbase0)*64;
  const u16* vbase = vTc + (size_t)bh*64*4096 + (size_t)kbase0;

  float l_run = 0.f;
  f32x4 oacc[4] = {};   // O^T[d = n*16+lg*4+r][q = l15]

  const int sr = tid >> 3, ssc = (tid & 7) ^ (sr & 7);

  // prologue: stage K0,K1,K2,V0,V1 (relative); drain; QK^T(0)
  gload16(kbase + (size_t)sr*64 + ssc*8,            &Ks[0][tid*8]);
  gload16(kbase + (size_t)(64+sr)*64 + ssc*8,       &Ks[1][tid*8]);
  gload16(kbase + (size_t)(128+sr)*64 + ssc*8,      &Ks[2][tid*8]);
  gload16(vbase + (size_t)sr*4096 + ssc*8,          &Vs[0][tid*8]);
  gload16(vbase + (size_t)sr*4096 + 64 + ssc*8,     &Vs[1][tid*8]);
  asm volatile("s_waitcnt vmcnt(0)" ::: "memory");
  __builtin_amdgcn_s_barrier();

  f32x4 stA[4], stB[4];
  #pragma unroll
  for (int n=0;n<4;n++){
    int R = n*16 + l15;
    f32x4 a_ = {};
    #pragma unroll
    for (int kk=0;kk<2;kk++){
      short8 ka = *(const short8*)&Ks[0][R*64 + (((kk<<2)+lg) ^ (R&7))*8];
      a_ = mfma16(ka, bq[kk], a_);
    }
    stA[n] = a_;
  }
  // Ks[0] first overwritten in body 1 (after body 0's end barrier).

  for (int kt = 0; kt < brun; kt += 4){
    AT_BODY(kt+0, 1, 3, 0, 2, stA, stB)
    AT_BODY(kt+1, 2, 0, 1, 3, stB, stA)
    AT_BODY(kt+2, 3, 1, 2, 0, stA, stB)
    AT_BODY(kt+3, 0, 2, 3, 1, stB, stA)
  }

  // cross-lane l reduction once (sum is linear across bodies)
  l_run += __shfl_xor(l_run, 16);
  l_run += __shfl_xor(l_run, 32);

  // write bf16 O-partials: po[kv][bh][qrow][d]; f32 pl[kv][bh][qrow]
  const int qrow = qt*128 + w*16 + l15;
  u16* pob = po + (((size_t)kv*24 + bh)*4096 + qrow)*64;
  #pragma unroll
  for (int n=0;n<4;n++){
    unsigned q01 = (unsigned)f2b(oacc[n][0]) | ((unsigned)f2b(oacc[n][1]) << 16);
    unsigned q23 = (unsigned)f2b(oacc[n][2]) | ((unsigned)f2b(oacc[n][3]) << 16);
    *(unsigned*)&pob[n*16 + lg*4]     = q01;
    *(unsigned*)&pob[n*16 + lg*4 + 2] = q23;
  }
  if (lg == 0) pl[((size_t)kv*24 + bh)*4096 + qrow] = l_run;
}

// ---------------- combine: o = (O0+O1)/(l0+l1), masked-q -> mean(V) ---------
__global__ __launch_bounds__(256) void comb_k(const u16* __restrict__ po,
    const float* __restrict__ pl, const int* __restrict__ mask,
    const float* __restrict__ vm, u16* __restrict__ o)
{
  int row = blockIdx.x;            // b*4096 + s
  int b = row >> 12, s = row & 4095;
  bool fq = mask[row] != 0;
  int t = threadIdx.x;
  #pragma unroll
  for (int i=0;i<3;i++){
    int j = t + i*256;             // 0..767 = h*64 + d
    int h = j >> 6, d = j & 63;
    size_t pi = (((size_t)b*12 + h)*4096 + s)*64 + d;
    size_t li = ((size_t)b*12 + h)*4096 + s;
    float O = b2f(po[pi]) + b2f(po[(size_t)24*4096*64 + pi]);
    float L = pl[li] + pl[(size_t)24*4096 + li];
    float v = fq ? O / L : vm[(b*12 + h)*64 + d]*(1.f/4096.f);
    o[(size_t)row*768 + j] = f2b(v);
  }
}

// ---------------------------------------------------------------------------
extern "C" void kernel_launch(void* const* d_in, const int* in_sizes, int n_in,
                              void* d_out, int out_size, void* d_ws, size_t ws_size,
                              hipStream_t stream)
{
  const float* x    = (const float*)d_in[0];
  const float* cosb = (const float*)d_in[1];
  const float* sinb = (const float*)d_in[2];
  const float* c    = (const float*)d_in[3];
  const int* amask  = (const int*)d_in[4];
  const float* ln1w = (const float*)d_in[5];
  const float* Wqkv = (const float*)d_in[6];
  const float* Wout = (const float*)d_in[7];
  const float* ln2w = (const float*)d_in[8];
  const float* W1   = (const float*)d_in[9];
  const float* b1   = (const float*)d_in[10];
  const float* W2   = (const float*)d_in[11];
  const float* b2   = (const float*)d_in[12];
  const float* Wada = (const float*)d_in[13];
  const float* bada = (const float*)d_in[14];

  char* ws = (char*)d_ws;
  size_t off = 0;
  auto take = [&](size_t bytes)->char*{
    char* p = ws + off; off = (off + bytes + 255) & ~(size_t)255; return p;
  };
  float* modb = (float*)take(9216*sizeof(float));
  float* vmean= (float*)take(24*64*sizeof(float));
  int*   idx  = (int*)take(8192*sizeof(int));
  int*   nvld = (int*)take(2*sizeof(int));
  u16* hdn  = (u16*)take((size_t)8192*768*2);    // ln1 out; pl aliases; h2 later
  u16* bufA = (u16*)take((size_t)8192*3072*2);   // po aliases; MLP mid later
  u16* vS   = (u16*)take((size_t)8192*768*2);    // v (s-major, RoPE'd)
  u16* qTb  = (u16*)take((size_t)8192*768*2);
  u16* kTb  = (u16*)take((size_t)8192*768*2);    // k (s-major, RoPE'd)
  u16* kc   = (u16*)take((size_t)8192*768*2);    // compacted K rows
  u16* vTc  = (u16*)take((size_t)8192*768*2);    // compacted V, d-major
  u16* ob   = (u16*)take((size_t)8192*768*2);    // attention output (bf16)
  u16* WqkvB= (u16*)take((size_t)2304*768*2);
  u16* WoutB= (u16*)take((size_t)768*768*2);
  u16* W1B  = (u16*)take((size_t)3072*768*2);
  u16* W2B  = (u16*)take((size_t)768*3072*2);
  float* out = (float*)d_out;
  float* x1 = out;                               // reuse d_out for x1 (f32)
  u16*   po = (u16*)bufA;                        // 2*24*4096*64 bf16 = 25.2MB
  float* pl = (float*)hdn;                       // 2*24*4096 f32 = 0.8MB

  prep_k<<<9218, 256, 0, stream>>>(Wqkv, WqkvB, Wout, WoutB, W1, W1B, W2, W2B,
                                   amask, idx, nvld, vmean, c, Wada, bada, modb);
  ln_mod_k<<<2048, 256, 0, stream>>>(x, hdn, ln1w, modb, 0, 1);
  gemm_k<4><<<dim3(64,18), 256, 0, stream>>>(hdn, WqkvB, nullptr, 8192, 2304, 768,
                                             nullptr, nullptr, nullptr,
                                             cosb, sinb, qTb, kTb, vS);
  gathv_k<<<dim3(80,24), 256, 0, stream>>>(kTb, vS, idx, nvld, kc, vTc, vmean);
  attn_k <<<dim3(32,24,2), 512, 0, stream>>>(qTb, kc, vTc, nvld, po, pl);
  comb_k <<<8192, 256, 0, stream>>>(po, pl, amask, vmean, ob);
  gemm_k<1><<<dim3(64,6), 256, 0, stream>>>(ob, WoutB, x1, 8192, 768, 768,
                                            x, modb, nullptr,
                                            nullptr, nullptr, nullptr, nullptr, nullptr);
  ln_mod_k<<<2048, 256, 0, stream>>>(x1, hdn, ln2w, modb, 3, 4);
  gemm_k<2><<<dim3(64,24), 256, 0, stream>>>(hdn, W1B, bufA, 8192, 3072, 768,
                                             nullptr, nullptr, b1,
                                             nullptr, nullptr, nullptr, nullptr, nullptr);
  gemm_k<3><<<dim3(64,6), 256, 0, stream>>>(bufA, W2B, out, 8192, 768, 3072,
                                            x1, modb, b2,
                                            nullptr, nullptr, nullptr, nullptr, nullptr);
}